// Round 1
// 957.050 us; speedup vs baseline: 1.0112x; 1.0112x over previous
//
#include <hip/hip_runtime.h>

typedef _Float16 h2 __attribute__((ext_vector_type(2)));
typedef _Float16 h4 __attribute__((ext_vector_type(4)));
typedef _Float16 h8 __attribute__((ext_vector_type(8)));
typedef float f4v __attribute__((ext_vector_type(4)));

#define U_DIM 256
#define M_DIM 256
#define T_DIM 512

#if defined(__has_builtin)
#if __has_builtin(__builtin_amdgcn_fdot2)
#define HAVE_FDOT2 1
#endif
#endif

__device__ __forceinline__ float fdot2f(h2 a, h2 b, float c) {
#ifdef HAVE_FDOT2
  return __builtin_amdgcn_fdot2(a, b, c, false);
#else
  return fmaf((float)a[0], (float)b[0], fmaf((float)a[1], (float)b[1], c));
#endif
}

__device__ __forceinline__ float fast_sigmoid(float z) {
  return __builtin_amdgcn_rcpf(1.f + __expf(-z));
}
__device__ __forceinline__ float fast_tanh(float z) {
  return fmaf(2.f, __builtin_amdgcn_rcpf(1.f + __expf(-2.f * z)), -1.f);
}

// DPP butterfly add over 8-lane groups (lanes [8a,8a+8)): masks {1,2,7} are a
// basis of (Z2)^3; xor1/xor2 are quad_perm, xor7 is row_half_mirror -- all
// VALU, zero LDS-pipe traffic (the old __shfl_xor path was ds_swizzle).
template <int CTRL>
__device__ __forceinline__ float dpp_xadd(float x) {
  int y = __builtin_amdgcn_update_dpp(0, __float_as_int(x), CTRL, 0xF, 0xF, true);
  return x + __int_as_float(y);
}
__device__ __forceinline__ float reduce8(float x) {
  x = dpp_xadd<0xB1>(x);   // quad_perm [1,0,3,2] : xor 1
  x = dpp_xadd<0x4E>(x);   // quad_perm [2,3,0,1] : xor 2
  x = dpp_xadd<0x141>(x);  // row_half_mirror     : xor 7
  return x;
}

// ---------------- prep: x fp32 -> fp16 (same [M][T][256] layout) ------------
__global__ void conv_x(const float* __restrict__ x, h8* __restrict__ x16, int n8) {
  int i = blockIdx.x * 256 + threadIdx.x;
  if (i >= n8) return;
  const float4* p = (const float4*)(x + (size_t)i * 8);
  float4 v0 = p[0], v1 = p[1];
  h8 o = {(_Float16)v0.x, (_Float16)v0.y, (_Float16)v0.z, (_Float16)v0.w,
          (_Float16)v1.x, (_Float16)v1.y, (_Float16)v1.z, (_Float16)v1.w};
  x16[i] = o;
}

// ------- prep: x-projection weights -> fp16 TRANSPOSED [mtx][n][k] ----------
__global__ void prep_xw(const float* __restrict__ wux, const float* __restrict__ wrx,
                        const float* __restrict__ wcx, h8* __restrict__ wt16) {
  int idx = blockIdx.x * 256 + threadIdx.x;   // 0..24575
  int mtx = idx >> 13;
  int rem = idx & 8191;
  int n = rem >> 5;
  int kv = rem & 31;
  const float* W = (mtx == 0) ? wux : ((mtx == 1) ? wrx : wcx);
  h8 o;
#pragma unroll
  for (int e = 0; e < 8; ++e) o[e] = (_Float16)W[(size_t)(kv * 8 + e) * U_DIM + n];
  wt16[idx] = o;
}

// ---------------- prep: recurrent weights fp16, K32/R4 layout ---------------
// Thread tid = 8g+s owns outputs col=4g+o (o=0..3) and k-slice [32s,32s+32).
// w16[(mtx*512+tid)*16 + (o*4+v)][e] = W[32s + 8v + e][4g + o]
__global__ void prep_w(const float* __restrict__ wuc, const float* __restrict__ wrc,
                       const float* __restrict__ wcc, h8* __restrict__ w16) {
  int idx = blockIdx.x * 256 + threadIdx.x;   // 0..24575
  int mtx = idx >> 13;
  int rem = idx & 8191;
  int tid = rem >> 4;
  int q   = rem & 15;
  int o = q >> 2, v = q & 3;
  int g = tid >> 3, s = tid & 7;
  const float* W = (mtx == 0) ? wuc : ((mtx == 1) ? wrc : wcc);
  int col = 4 * g + o;
  int k0 = 32 * s + 8 * v;
  h8 out;
#pragma unroll
  for (int e = 0; e < 8; ++e) out[e] = (_Float16)W[(size_t)(k0 + e) * U_DIM + col];
  w16[idx] = out;
}

// ---------------- xproj via fp16 MFMA, fp16 OUTPUT (unchanged) --------------
__global__ __launch_bounds__(256, 2)
void xproj_mfma(const h8* __restrict__ x16, const h8* __restrict__ wt16,
                const float* __restrict__ Bu, const float* __restrict__ Br,
                const float* __restrict__ Bc,
                _Float16* __restrict__ XU, _Float16* __restrict__ XR,
                _Float16* __restrict__ XC, int t0, int len) {
  const int mtx = blockIdx.z;
  const float* Bv = (mtx == 0) ? Bu : ((mtx == 1) ? Br : Bc);
  _Float16* O = (mtx == 0) ? XU : ((mtx == 1) ? XR : XC);
  const h8* W = wt16 + (size_t)mtx * 256 * 32;

  __shared__ _Float16 a_sh[128][40];
  __shared__ _Float16 b_sh[128][40];

  const int tid = threadIdx.x;
  const int r0 = blockIdx.x * 128;
  const int c0 = blockIdx.y * 128;

  const int srow = tid >> 1;
  const int spart = tid & 1;
  const int r = r0 + srow;
  const int mm = r / len;
  const int tc = r - mm * len;
  const h8* arow = x16 + ((size_t)mm * T_DIM + (size_t)(t0 + tc)) * 32;
  const h8* brow = W + (size_t)(c0 + srow) * 32;

  const int lane = tid & 63;
  const int w = tid >> 6;
  const int quad = lane >> 4;
  const int mrow = lane & 15;

  f4v acc[2][8];
#pragma unroll
  for (int fr = 0; fr < 2; ++fr)
#pragma unroll
    for (int fc = 0; fc < 8; ++fc) acc[fr][fc] = f4v{0.f, 0.f, 0.f, 0.f};

  for (int k8 = 0; k8 < 32; k8 += 4) {
    h8 a0 = arow[k8 + 2 * spart];
    h8 a1 = arow[k8 + 2 * spart + 1];
    h8 b0 = brow[k8 + 2 * spart];
    h8 b1 = brow[k8 + 2 * spart + 1];
    __syncthreads();
    *(h8*)&a_sh[srow][spart * 16]     = a0;
    *(h8*)&a_sh[srow][spart * 16 + 8] = a1;
    *(h8*)&b_sh[srow][spart * 16]     = b0;
    *(h8*)&b_sh[srow][spart * 16 + 8] = b1;
    __syncthreads();
    h8 af0 = *(const h8*)&a_sh[32 * w + mrow][quad * 8];
    h8 af1 = *(const h8*)&a_sh[32 * w + 16 + mrow][quad * 8];
#pragma unroll
    for (int fc = 0; fc < 8; ++fc) {
      h8 bf = *(const h8*)&b_sh[fc * 16 + mrow][quad * 8];
      acc[0][fc] = __builtin_amdgcn_mfma_f32_16x16x32_f16(af0, bf, acc[0][fc], 0, 0, 0);
      acc[1][fc] = __builtin_amdgcn_mfma_f32_16x16x32_f16(af1, bf, acc[1][fc], 0, 0, 0);
    }
  }

#pragma unroll
  for (int fc = 0; fc < 8; ++fc) {
    int col = c0 + fc * 16 + mrow;
    float bb = Bv[col];
#pragma unroll
    for (int fr = 0; fr < 2; ++fr)
#pragma unroll
      for (int reg = 0; reg < 4; ++reg) {
        int rr = r0 + 32 * w + fr * 16 + quad * 4 + reg;
        O[(size_t)rr * U_DIM + col] = (_Float16)(acc[fr][fc][reg] + bb);
      }
  }
}

// ---------------- recurrence: K32/R4 register-blocked, DPP reduce -----------
// Old structure was LDS-return-BW bound: 256 ds_read_b128/CU-step (~3070 cyc
// of the 3420-cyc step).  New map: thread = (g=tid>>3 owns outputs 4g..4g+3,
// s=tid&7 owns k in [32s,32s+32)).  Weight regs unchanged (3*4*32*2B = 192
// VGPR), fdot2 count unchanged (192/thr/step), but LDS reads drop 4x to
// 8 b128/thr/step.  Reduction over 8 lanes is pure-VALU DPP (xor 1,2,7) --
// nothing added to the LDS pipe.  Chunk base 5s puts the 8 broadcast groups
// on disjoint 4-bank spans (banks 20s+4v mod 32: all distinct) -> 0 conflicts.
__global__ __launch_bounds__(512, 2)
void gru_rec(const _Float16* __restrict__ XU, const _Float16* __restrict__ XR,
             const _Float16* __restrict__ XC, const h8* __restrict__ w16,
             const float* __restrict__ c_in, float* __restrict__ c_out, int len) {
  const int m = blockIdx.x;
  const int tid = threadIdx.x;
  const int g = tid >> 3;
  const int s = tid & 7;
  const int so = s & 3;
  const int cb = 5 * s;                       // h8 chunk base (bank-spread)
  const int j = 4 * g + so;                   // owned output (dup on s, s+4)
  const int hwj = 40 * (j >> 5) + (j & 31);   // halfword index in padded LDS
  const bool wr_lane = (s < 4);

  __shared__ h8 ch8[40];
  __shared__ h8 hh8[40];
  _Float16* cwp = (_Float16*)ch8;
  _Float16* hwp = (_Float16*)hh8;

  const h8* wub = w16 + (size_t)tid * 16;
  const h8* wrb = wub + 8192;
  const h8* wcb = wub + 16384;

#define DECL_W(l) h8 wu##l = wub[l]; h8 wr##l = wrb[l]; h8 wc##l = wcb[l];
  DECL_W(0)  DECL_W(1)  DECL_W(2)  DECL_W(3)
  DECL_W(4)  DECL_W(5)  DECL_W(6)  DECL_W(7)
  DECL_W(8)  DECL_W(9)  DECL_W(10) DECL_W(11)
  DECL_W(12) DECL_W(13) DECL_W(14) DECL_W(15)
#undef DECL_W

  float cj = c_in[m * U_DIM + j];
  if (wr_lane) cwp[hwj] = (_Float16)cj;

  const _Float16* XUb = XU + (size_t)m * len * U_DIM;
  const _Float16* XRb = XR + (size_t)m * len * U_DIM;
  const _Float16* XCb = XC + (size_t)m * len * U_DIM;

  int off = j;
  float xuv = (float)XUb[off], xrv = (float)XRb[off], xcv = (float)XCb[off];

  __syncthreads();

#define P1O(cv, l, o)                                                     \
  pu##o = fdot2f(h2{cv[0], cv[1]}, h2{wu##l[0], wu##l[1]}, pu##o);        \
  pu##o = fdot2f(h2{cv[2], cv[3]}, h2{wu##l[2], wu##l[3]}, pu##o);        \
  pu##o = fdot2f(h2{cv[4], cv[5]}, h2{wu##l[4], wu##l[5]}, pu##o);        \
  pu##o = fdot2f(h2{cv[6], cv[7]}, h2{wu##l[6], wu##l[7]}, pu##o);        \
  pr##o = fdot2f(h2{cv[0], cv[1]}, h2{wr##l[0], wr##l[1]}, pr##o);        \
  pr##o = fdot2f(h2{cv[2], cv[3]}, h2{wr##l[2], wr##l[3]}, pr##o);        \
  pr##o = fdot2f(h2{cv[4], cv[5]}, h2{wr##l[4], wr##l[5]}, pr##o);        \
  pr##o = fdot2f(h2{cv[6], cv[7]}, h2{wr##l[6], wr##l[7]}, pr##o);
#define PASS1V(v, la, lb, lc, ld) { h8 cv = ch8[cb + v];                  \
  P1O(cv, la, 0) P1O(cv, lb, 1) P1O(cv, lc, 2) P1O(cv, ld, 3) }

#define P2O(hv, l, o)                                                     \
  pc##o = fdot2f(h2{hv[0], hv[1]}, h2{wc##l[0], wc##l[1]}, pc##o);        \
  pc##o = fdot2f(h2{hv[2], hv[3]}, h2{wc##l[2], wc##l[3]}, pc##o);        \
  pc##o = fdot2f(h2{hv[4], hv[5]}, h2{wc##l[4], wc##l[5]}, pc##o);        \
  pc##o = fdot2f(h2{hv[6], hv[7]}, h2{wc##l[6], wc##l[7]}, pc##o);
#define PASS2V(v, la, lb, lc, ld) { h8 hv = hh8[cb + v];                  \
  P2O(hv, la, 0) P2O(hv, lb, 1) P2O(hv, lc, 2) P2O(hv, ld, 3) }

  for (int t = 0; t < len; ++t) {
    int offn = off + ((t + 1 < len) ? U_DIM : 0);
    float nxu = (float)XUb[offn], nxr = (float)XRb[offn], nxc = (float)XCb[offn];

    float pu0 = 0.f, pu1 = 0.f, pu2 = 0.f, pu3 = 0.f;
    float pr0 = 0.f, pr1 = 0.f, pr2 = 0.f, pr3 = 0.f;
    PASS1V(0, 0, 4, 8, 12)
    PASS1V(1, 1, 5, 9, 13)
    PASS1V(2, 2, 6, 10, 14)
    PASS1V(3, 3, 7, 11, 15)

    pu0 = reduce8(pu0); pu1 = reduce8(pu1); pu2 = reduce8(pu2); pu3 = reduce8(pu3);
    pr0 = reduce8(pr0); pr1 = reduce8(pr1); pr2 = reduce8(pr2); pr3 = reduce8(pr3);

    float puj = (so & 2) ? ((so & 1) ? pu3 : pu2) : ((so & 1) ? pu1 : pu0);
    float prj = (so & 2) ? ((so & 1) ? pr3 : pr2) : ((so & 1) ? pr1 : pr0);
    float gu = fast_sigmoid(puj + xuv);
    float gr = fast_sigmoid(prj + xrv);
    if (wr_lane) hwp[hwj] = (_Float16)(gr * cj);
    __syncthreads();

    float pc0 = 0.f, pc1 = 0.f, pc2 = 0.f, pc3 = 0.f;
    PASS2V(0, 0, 4, 8, 12)
    PASS2V(1, 1, 5, 9, 13)
    PASS2V(2, 2, 6, 10, 14)
    PASS2V(3, 3, 7, 11, 15)

    pc0 = reduce8(pc0); pc1 = reduce8(pc1); pc2 = reduce8(pc2); pc3 = reduce8(pc3);
    float pcj = (so & 2) ? ((so & 1) ? pc3 : pc2) : ((so & 1) ? pc1 : pc0);

    float cand = fast_tanh(pcj + xcv);
    cj = fmaf(gu, cand - cj, cj);
    if (wr_lane) cwp[hwj] = (_Float16)cj;

    xuv = nxu; xrv = nxr; xcv = nxc; off = offn;
    __syncthreads();
  }

#undef P1O
#undef PASS1V
#undef P2O
#undef PASS2V

  if (wr_lane) c_out[m * U_DIM + j] = cj;
}

// ---------------- host ------------------------------------------------------
extern "C" void kernel_launch(void* const* d_in, const int* in_sizes, int n_in,
                              void* d_out, int out_size, void* d_ws, size_t ws_size,
                              hipStream_t stream) {
  const float* x   = (const float*)d_in[0];
  const float* a0  = (const float*)d_in[1];
  const float* wcx = (const float*)d_in[2];
  const float* wcc = (const float*)d_in[3];
  const float* bc  = (const float*)d_in[4];
  const float* wux = (const float*)d_in[5];
  const float* wuc = (const float*)d_in[6];
  const float* bu  = (const float*)d_in[7];
  const float* wrx = (const float*)d_in[8];
  const float* wrc = (const float*)d_in[9];
  const float* br  = (const float*)d_in[10];
  float* out = (float*)d_out;

  const size_t x16_bytes = (size_t)M_DIM * T_DIM * U_DIM * 2;  // 67.1 MB
  const size_t wt_bytes  = 3ull * 256 * 32 * 16;               // 384 KB
  const size_t w16_bytes = 3ull * 512 * 16 * 16;               // 384 KB
  const size_t fixed = x16_bytes + wt_bytes + w16_bytes;

  h8* x16  = (h8*)d_ws;
  h8* wt16 = (h8*)((char*)d_ws + x16_bytes);
  h8* w16  = (h8*)((char*)d_ws + x16_bytes + wt_bytes);
  _Float16* XU0 = (_Float16*)((char*)d_ws + fixed);

  size_t avail = (ws_size > fixed) ? (ws_size - fixed) : 0;
  const size_t perT = 3ull * M_DIM * U_DIM * 2;                // 393 KB / step
  int Tc = (int)(avail / perT);
  if (Tc > T_DIM) Tc = T_DIM;
  if (Tc < 1) Tc = 1;
  int nch = (T_DIM + Tc - 1) / Tc;
  Tc = (T_DIM + nch - 1) / nch;

  _Float16* XU = XU0;
  _Float16* XR = XU + (size_t)M_DIM * Tc * U_DIM;
  _Float16* XC = XR + (size_t)M_DIM * Tc * U_DIM;

  conv_x<<<16384, 256, 0, stream>>>(x, x16, M_DIM * T_DIM * U_DIM / 8);
  prep_xw<<<96, 256, 0, stream>>>(wux, wrx, wcx, wt16);
  prep_w<<<96, 256, 0, stream>>>(wuc, wrc, wcc, w16);

  for (int t0 = 0; t0 < T_DIM; t0 += Tc) {
    int lenc = (T_DIM - t0) < Tc ? (T_DIM - t0) : Tc;
    dim3 g((M_DIM * lenc) / 128, 2, 3);
    xproj_mfma<<<g, 256, 0, stream>>>(x16, wt16, bu, br, bc,
                                      XU, XR, XC, t0, lenc);
    gru_rec<<<M_DIM, 512, 0, stream>>>(XU, XR, XC, w16,
                                       (t0 == 0 ? a0 : out), out, lenc);
  }
}